// Round 2
// baseline (996.201 us; speedup 1.0000x reference)
//
#include <hip/hip_runtime.h>
#include <hip/hip_bf16.h>

#define NN 384
#define MM 32
#define KK 32

typedef __attribute__((ext_vector_type(8))) __bf16 bf16x8;
typedef __attribute__((ext_vector_type(4))) float f32x4;

__device__ __forceinline__ void split8(const float* v, bf16x8& hi, bf16x8& lo) {
#pragma unroll
    for (int t = 0; t < 8; ++t) {
        float f = v[t];
        __bf16 h = (__bf16)f;
        hi[t] = h;
        lo[t] = (__bf16)(f - (float)h);
    }
}

// One wave (64 lanes) handles one (i,j) pair: S = Q*K^T (32x32, K=32),
// softmax over cols, * mask, O = P*Q. bf16x3 split for fp32-grade accuracy.
__global__ __launch_bounds__(256) void attn_pair_kernel(
    const float* __restrict__ x1,
    const float* __restrict__ mask,
    float* __restrict__ out)
{
    // per-wave LDS: S^T (32 rows of b, pitch 36 floats) and P hi/lo bf16 (pitch 40)
    __shared__ __align__(16) float  sST[4][32 * 36];
    __shared__ __align__(16) __bf16 sPhi[4][32 * 40];
    __shared__ __align__(16) __bf16 sPlo[4][32 * 40];

    const int tid  = threadIdx.x;
    const int w    = tid >> 6;     // wave id in block
    const int l    = tid & 63;     // lane
    const int m16  = l & 15;
    const int quad = l >> 4;

    const unsigned p = blockIdx.x * 4u + (unsigned)w;   // pair index = i*384 + j
    const unsigned i = p / NN;
    const unsigned j = p - i * NN;

    const float* Q  = x1 + (size_t)j * (MM * KK);   // query == value tile
    const float* Kt = x1 + (size_t)i * (MM * KK);   // key tile

    // ---- fragments for S = Q * K^T  (A[m][k]=Q[m][k], B[k][n]=Kt[n][k]) ----
    // A-layout: A[m=lane&15][k=quad*8+jj]; B-layout: B[k=quad*8+jj][n=lane&15]
    bf16x8 aQh[2], aQl[2], bKh[2], bKl[2];
#pragma unroll
    for (int h = 0; h < 2; ++h) {
        const int row = h * 16 + m16;
        float qbuf[8], kbuf[8];
        *(float4*)&qbuf[0] = *(const float4*)(Q  + row * KK + quad * 8);
        *(float4*)&qbuf[4] = *(const float4*)(Q  + row * KK + quad * 8 + 4);
        *(float4*)&kbuf[0] = *(const float4*)(Kt + row * KK + quad * 8);
        *(float4*)&kbuf[4] = *(const float4*)(Kt + row * KK + quad * 8 + 4);
        split8(qbuf, aQh[h], aQl[h]);
        split8(kbuf, bKh[h], bKl[h]);
    }

    f32x4 S[2][2];
#pragma unroll
    for (int ma = 0; ma < 2; ++ma)
#pragma unroll
        for (int nb = 0; nb < 2; ++nb) {
            f32x4 c = {0.f, 0.f, 0.f, 0.f};
            c = __builtin_amdgcn_mfma_f32_16x16x32_bf16(aQl[ma], bKh[nb], c, 0, 0, 0);
            c = __builtin_amdgcn_mfma_f32_16x16x32_bf16(aQh[ma], bKl[nb], c, 0, 0, 0);
            c = __builtin_amdgcn_mfma_f32_16x16x32_bf16(aQh[ma], bKh[nb], c, 0, 0, 0);
            S[ma][nb] = c;
        }

    // ---- write S^T to LDS: ST[b][a], float4 along a (C rows are consecutive) ----
#pragma unroll
    for (int ma = 0; ma < 2; ++ma)
#pragma unroll
        for (int nb = 0; nb < 2; ++nb) {
            const int b  = nb * 16 + m16;
            const int a0 = ma * 16 + quad * 4;
            *(f32x4*)&sST[w][b * 36 + a0] = S[ma][nb];
        }

    __syncthreads();

    // ---- softmax over b: lane handles row a = l>>1, half b0 = (l&1)*16 ----
    const int a  = l >> 1;
    const int b0 = (l & 1) * 16;
    float s[16];
#pragma unroll
    for (int t = 0; t < 16; ++t) s[t] = sST[w][(b0 + t) * 36 + a];

    float mx = s[0];
#pragma unroll
    for (int t = 1; t < 16; ++t) mx = fmaxf(mx, s[t]);
    mx = fmaxf(mx, __shfl_xor(mx, 1, 64));

    float sum = 0.f;
#pragma unroll
    for (int t = 0; t < 16; ++t) { s[t] = __expf(s[t] - mx); sum += s[t]; }
    sum += __shfl_xor(sum, 1, 64);
    const float rinv = 1.0f / sum;

    // ---- dropout mask (coalesced stream read) ----
    const float* mrow = mask + (size_t)p * (MM * MM) + a * MM + b0;
    float mk[16];
    *(float4*)&mk[0]  = *(const float4*)(mrow + 0);
    *(float4*)&mk[4]  = *(const float4*)(mrow + 4);
    *(float4*)&mk[8]  = *(const float4*)(mrow + 8);
    *(float4*)&mk[12] = *(const float4*)(mrow + 12);

    float pv[16];
#pragma unroll
    for (int t = 0; t < 16; ++t) pv[t] = s[t] * rinv * mk[t];

    bf16x8 ph, plo;
    split8(&pv[0], ph, plo);
    *(bf16x8*)&sPhi[w][a * 40 + b0] = ph;
    *(bf16x8*)&sPlo[w][a * 40 + b0] = plo;
    split8(&pv[8], ph, plo);
    *(bf16x8*)&sPhi[w][a * 40 + b0 + 8] = ph;
    *(bf16x8*)&sPlo[w][a * 40 + b0 + 8] = plo;

    __syncthreads();

    // ---- O = P * Q : A[m=a][k=b]=P, B[k=b][n=k_out]=Q[b][k_out] ----
    bf16x8 aPh[2], aPl[2], bVh[2], bVl[2];
#pragma unroll
    for (int h = 0; h < 2; ++h) {
        aPh[h] = *(const bf16x8*)&sPhi[w][(h * 16 + m16) * 40 + quad * 8];
        aPl[h] = *(const bf16x8*)&sPlo[w][(h * 16 + m16) * 40 + quad * 8];
        const float* vp = Q + (quad * 8) * KK + (h * 16 + m16);
        float vbuf[8];
#pragma unroll
        for (int jj = 0; jj < 8; ++jj) vbuf[jj] = vp[jj * KK];
        split8(vbuf, bVh[h], bVl[h]);
    }

    f32x4 O[2][2];
#pragma unroll
    for (int ma = 0; ma < 2; ++ma)
#pragma unroll
        for (int nk = 0; nk < 2; ++nk) {
            f32x4 c = {0.f, 0.f, 0.f, 0.f};
            c = __builtin_amdgcn_mfma_f32_16x16x32_bf16(aPl[ma], bVh[nk], c, 0, 0, 0);
            c = __builtin_amdgcn_mfma_f32_16x16x32_bf16(aPh[ma], bVl[nk], c, 0, 0, 0);
            c = __builtin_amdgcn_mfma_f32_16x16x32_bf16(aPh[ma], bVh[nk], c, 0, 0, 0);
            O[ma][nk] = c;
        }

    float* obase = out + (size_t)p * (MM * KK);
#pragma unroll
    for (int ma = 0; ma < 2; ++ma)
#pragma unroll
        for (int nk = 0; nk < 2; ++nk) {
            const int col = nk * 16 + m16;
            const int r0  = ma * 16 + quad * 4;
#pragma unroll
            for (int rr = 0; rr < 4; ++rr)
                obase[(r0 + rr) * KK + col] = O[ma][nk][rr];
        }
}

extern "C" void kernel_launch(void* const* d_in, const int* in_sizes, int n_in,
                              void* d_out, int out_size, void* d_ws, size_t ws_size,
                              hipStream_t stream) {
    const float* x1   = (const float*)d_in[0];
    const float* mask = (const float*)d_in[1];
    float* out = (float*)d_out;
    const int pairs = NN * NN;          // 147456
    dim3 grid(pairs / 4), block(256);   // 4 waves/block, 1 pair/wave
    attn_pair_kernel<<<grid, block, 0, stream>>>(x1, mask, out);
}